// Round 4
// baseline (100.214 us; speedup 1.0000x reference)
//
#include <hip/hip_runtime.h>

#define B_DIM   128
#define N_IN    16384
#define N_OUT   8192
#define N_EDGES (N_OUT * 64)

#define WAVES_PB 8                  // waves per block = outputs per block
#define J_BLK    WAVES_PB
#define THREADS  (WAVES_PB * 64)    // 512

#define CHUNKB   32                 // batch columns per chunk (2 MB working set)
#define NCHUNK   (B_DIM / CHUNKB)   // 4
#define JGROUPS  (N_OUT / J_BLK)    // 1024

__device__ __forceinline__ int lower_bound_dev(const int* __restrict__ a, int n, int v) {
    int lo = 0, hi = n;
    while (lo < hi) {
        int mid = (lo + hi) >> 1;
        if (a[mid] < v) lo = mid + 1; else hi = mid;
    }
    return lo;
}

// rp[j] = first edge index with dst >= j (j in [0, N_OUT]), via boundary scatter.
__global__ void build_rowptr_kernel(const int* __restrict__ dst, int* __restrict__ rp) {
    const int e = blockIdx.x * blockDim.x + threadIdx.x;
    if (e >= N_EDGES) return;
    const int d     = dst[e];
    const int dprev = (e == 0) ? -1 : dst[e - 1];
    for (int j = dprev + 1; j <= d; ++j) rp[j] = e;
    if (e == N_EDGES - 1)
        for (int j = d + 1; j <= N_OUT; ++j) rp[j] = N_EDGES;
}

// x[B][N_IN] -> xT[N_IN][B], 32x32 LDS tiles, both sides coalesced
__global__ __launch_bounds__(256) void transpose_kernel(const float* __restrict__ x,
                                                        float* __restrict__ xT) {
    __shared__ float tile[32][33];
    const int i0 = blockIdx.x * 32;
    const int b0 = blockIdx.y * 32;
    const int tx = threadIdx.x;
    const int ty = threadIdx.y;
#pragma unroll
    for (int r = 0; r < 32; r += 8)
        tile[ty + r][tx] = x[(size_t)(b0 + ty + r) * N_IN + (i0 + tx)];
    __syncthreads();
#pragma unroll
    for (int r = 0; r < 32; r += 8)
        xT[(size_t)(i0 + ty + r) * B_DIM + (b0 + tx)] = tile[tx][ty + r];
}

// Batch-chunked gather kernel. blockIdx.x = jgroup + JGROUPS*chunk, so all
// blocks of chunk c run (roughly) before chunk c+1: each chunk's xT slice is
// 16384 rows x 128 B = 2 MB -> resident in every XCD's 4 MB L2. One wave per
// output j: lane = (slot = lane>>3 -> edge e+slot, bl = lane&7 -> float4 over
// 32 batch cols). 8 edges per gather instruction, shfl_xor tree over slots,
// LDS-transposed coalesced epilogue. Each (b,j) written by exactly one block.
__global__ __launch_bounds__(THREADS, 8) void sparse_layer_chunked(
        const float* __restrict__ xT, const float* __restrict__ w,
        const float* __restrict__ bias, const int* __restrict__ src,
        const int* __restrict__ rp, float* __restrict__ y) {
    __shared__ float tile[J_BLK][36];   // 36: 16B-aligned rows for float4 stores

    const int tid   = threadIdx.x;
    const int wid   = tid >> 6;
    const int lane  = tid & 63;
    const int slot  = lane >> 3;        // edge slot 0..7
    const int bl    = lane & 7;         // float4 index within 32-col chunk
    const int chunk = blockIdx.x >> 10; // JGROUPS = 1024
    const int jg    = blockIdx.x & (JGROUPS - 1);
    const int cb    = chunk * CHUNKB;   // chunk base batch column
    const int j0    = jg * J_BLK;
    const int j     = j0 + wid;

    const int e0 = __builtin_amdgcn_readfirstlane(rp[j]);
    const int e1 = __builtin_amdgcn_readfirstlane(rp[j + 1]);

    float4 acc = {0.f, 0.f, 0.f, 0.f};
    // Lane's gather base: row s -> xT + s*128 + cb + 4*bl
    const float* xbase = xT + cb + 4 * bl;

#pragma unroll 2
    for (int e = e0; e < e1; e += 8) {
        const int  ee    = e + slot;
        const bool valid = ee < e1;
        const int  ec    = valid ? ee : e0;   // e0 < e1 inside the loop
        const int  s     = src[ec];
        const float wt   = valid ? w[ec] : 0.f;
        const float4 v   = *(const float4*)(xbase + (size_t)s * B_DIM);
        acc.x = fmaf(v.x, wt, acc.x);
        acc.y = fmaf(v.y, wt, acc.y);
        acc.z = fmaf(v.z, wt, acc.z);
        acc.w = fmaf(v.w, wt, acc.w);
    }

    // Reduce over the 8 edge slots (lane bits 3..5).
#pragma unroll
    for (int m = 8; m <= 32; m <<= 1) {
        acc.x += __shfl_xor(acc.x, m, 64);
        acc.y += __shfl_xor(acc.y, m, 64);
        acc.z += __shfl_xor(acc.z, m, 64);
        acc.w += __shfl_xor(acc.w, m, 64);
    }

    if (slot == 0) {                         // lanes 0..7 hold b = cb + 4*bl .. +3
        *(float4*)&tile[wid][4 * bl] = acc;
    }
    __syncthreads();

    // Coalesced epilogue: 8 consecutive lanes -> 8 consecutive j (32B segments).
    if (tid < J_BLK * CHUNKB) {              // 256 threads
        const int jj = tid & (J_BLK - 1);
        const int bb = tid >> 3;             // 0..31
        const float v = tile[jj][bb] + bias[j0 + jj];
        y[(size_t)(cb + bb) * N_OUT + (j0 + jj)] = fmaxf(v, 0.f);
    }
}

// Fallback (no usable workspace): per-output wave, gathers from row-major x.
__global__ __launch_bounds__(THREADS) void sparse_layer_fallback(
        const float* __restrict__ x, const float* __restrict__ w,
        const float* __restrict__ bias, const int* __restrict__ src,
        const int* __restrict__ dst, float* __restrict__ y) {
    __shared__ float tile[J_BLK][130];
    __shared__ int   srp[J_BLK + 1];

    const int tid  = threadIdx.x;
    const int wid  = tid >> 6;
    const int lane = tid & 63;
    const int j0   = blockIdx.x * J_BLK;

    if (tid <= J_BLK) srp[tid] = lower_bound_dev(dst, N_EDGES, j0 + tid);
    __syncthreads();

    const int e0 = srp[wid], e1 = srp[wid + 1];
    const int b0 = lane * 2;
    float acc0 = 0.f, acc1 = 0.f;
    for (int e = e0; e < e1; ++e) {
        const int   s  = src[e];
        const float wt = w[e];
        acc0 = fmaf(x[(size_t)b0 * N_IN + s], wt, acc0);
        acc1 = fmaf(x[(size_t)(b0 + 1) * N_IN + s], wt, acc1);
    }
    tile[wid][b0]     = acc0;
    tile[wid][b0 + 1] = acc1;
    __syncthreads();
#pragma unroll
    for (int i = tid; i < B_DIM * J_BLK; i += THREADS) {
        const int bb = i >> 3;
        const int jj = i & (J_BLK - 1);
        const float v = tile[jj][bb] + bias[j0 + jj];
        y[(size_t)bb * N_OUT + (j0 + jj)] = fmaxf(v, 0.f);
    }
}

extern "C" void kernel_launch(void* const* d_in, const int* in_sizes, int n_in,
                              void* d_out, int out_size, void* d_ws, size_t ws_size,
                              hipStream_t stream) {
    const float* x    = (const float*)d_in[0];
    const float* w    = (const float*)d_in[1];
    const float* bias = (const float*)d_in[2];
    const int*   esrc = (const int*)d_in[3];
    const int*   edst = (const int*)d_in[4];
    float*       y    = (float*)d_out;

    const size_t RP_BYTES = (size_t)(N_OUT + 1) * sizeof(int);
    const size_t XT_OFF   = 65536;
    const size_t XT_BYTES = (size_t)N_IN * B_DIM * sizeof(float);

    const bool has_ws = ws_size >= XT_OFF + XT_BYTES && ws_size >= RP_BYTES;

    int*   rp = (int*)d_ws;
    float* xT = (float*)((char*)d_ws + XT_OFF);

    if (has_ws) {
        build_rowptr_kernel<<<(N_EDGES + 255) / 256, 256, 0, stream>>>(edst, rp);
        transpose_kernel<<<dim3(N_IN / 32, B_DIM / 32), dim3(32, 8), 0, stream>>>(x, xT);
        sparse_layer_chunked<<<dim3(JGROUPS * NCHUNK), THREADS, 0, stream>>>(xT, w, bias, esrc, rp, y);
    } else {
        sparse_layer_fallback<<<dim3(N_OUT / J_BLK), THREADS, 0, stream>>>(x, w, bias, esrc, edst, y);
    }
}

// Round 5
// 86.771 us; speedup vs baseline: 1.1549x; 1.1549x over previous
//
#include <hip/hip_runtime.h>
#include <hip/hip_fp16.h>

#define B_DIM   128
#define N_IN    16384
#define N_OUT   8192
#define N_EDGES (N_OUT * 64)

#define J_BLK    8                  // outputs (waves) per block
#define THREADS  (J_BLK * 64)       // 512
#define JGROUPS  (N_OUT / J_BLK)    // 1024

__device__ __forceinline__ int lower_bound_dev(const int* __restrict__ a, int n, int v) {
    int lo = 0, hi = n;
    while (lo < hi) {
        int mid = (lo + hi) >> 1;
        if (a[mid] < v) lo = mid + 1; else hi = mid;
    }
    return lo;
}

// rp[j] = first edge index with dst >= j (j in [0, N_OUT]), via boundary scatter.
__global__ void build_rowptr_kernel(const int* __restrict__ dst, int* __restrict__ rp) {
    const int e = blockIdx.x * blockDim.x + threadIdx.x;
    if (e >= N_EDGES) return;
    const int d     = dst[e];
    const int dprev = (e == 0) ? -1 : dst[e - 1];
    for (int j = dprev + 1; j <= d; ++j) rp[j] = e;
    if (e == N_EDGES - 1)
        for (int j = d + 1; j <= N_OUT; ++j) rp[j] = N_EDGES;
}

// x[B][N_IN] (fp32) -> xTh[N_IN][B] (fp16). Read coalesced, write 128B half2 rows.
// Working result: 4 MB total -> fits every XCD's 4 MB L2; halves gather bytes.
__global__ __launch_bounds__(256) void transpose_h_kernel(const float* __restrict__ x,
                                                          __half* __restrict__ xTh) {
    __shared__ float tile[64][33];      // [b_local][i_local]
    const int i0 = blockIdx.x * 32;
    const int b0 = blockIdx.y * 64;
    const int tx = threadIdx.x;         // 0..31
    const int ty = threadIdx.y;         // 0..7
#pragma unroll
    for (int r = 0; r < 64; r += 8)
        tile[ty + r][tx] = x[(size_t)(b0 + ty + r) * N_IN + (i0 + tx)];
    __syncthreads();
    __half2* out = (__half2*)xTh;
#pragma unroll
    for (int rr = 0; rr < 4; ++rr) {
        const int il = rr * 8 + ty;     // i_local 0..31
        const float a = tile[2 * tx][il];
        const float b = tile[2 * tx + 1][il];
        // 32 lanes x 4B = 128B contiguous store per instruction
        out[(size_t)(i0 + il) * (B_DIM / 2) + (b0 >> 1) + tx] = __floats2half2_rn(a, b);
    }
}

// One WAVE per output j. Lane = (slot = lane>>4 -> edge e+slot, bl = lane&15).
// Each lane float4-loads 16B = 8 fp16 batch elems of row src[e+slot]; 16 lanes
// cover the full 256B row. 4 edges per gather instruction, fp32 accumulate,
// 2-step shfl_xor reduce over slots, LDS-transposed coalesced epilogue.
__global__ __launch_bounds__(THREADS, 8) void sparse_layer_h(
        const __half* __restrict__ xTh, const float* __restrict__ w,
        const float* __restrict__ bias, const int* __restrict__ src,
        const int* __restrict__ rp, float* __restrict__ y) {
    __shared__ float tile[J_BLK][132];  // 132: 16B-aligned rows

    const int tid  = threadIdx.x;
    const int wid  = tid >> 6;
    const int lane = tid & 63;
    const int slot = lane >> 4;         // 0..3
    const int bl   = lane & 15;         // 16B chunk -> batch cols 8*bl .. 8*bl+7
    const int j0   = blockIdx.x * J_BLK;
    const int j    = j0 + wid;

    const int e0 = __builtin_amdgcn_readfirstlane(rp[j]);
    const int e1 = __builtin_amdgcn_readfirstlane(rp[j + 1]);

    float acc[8] = {0.f, 0.f, 0.f, 0.f, 0.f, 0.f, 0.f, 0.f};
    const char* xbase = (const char*)xTh + bl * 16;   // + row*256B

#pragma unroll 4
    for (int e = e0; e < e1; e += 4) {
        const int  ee    = e + slot;
        const bool valid = ee < e1;
        const int  ec    = valid ? ee : e0;           // e0 < e1 inside loop
        const int  s     = src[ec];
        const float wt   = valid ? w[ec] : 0.f;
        const float4 raw = *(const float4*)(xbase + (size_t)s * (B_DIM * 2));
        const __half2* hp = (const __half2*)&raw;
#pragma unroll
        for (int q = 0; q < 4; ++q) {
            const float2 f = __half22float2(hp[q]);
            acc[2 * q]     = fmaf(f.x, wt, acc[2 * q]);
            acc[2 * q + 1] = fmaf(f.y, wt, acc[2 * q + 1]);
        }
    }

    // Reduce over the 4 edge slots (lane bits 4..5).
#pragma unroll
    for (int m = 16; m <= 32; m <<= 1)
#pragma unroll
        for (int q = 0; q < 8; ++q) acc[q] += __shfl_xor(acc[q], m, 64);

    if (slot == 0) {                    // lanes 0..15 hold b = 8*bl .. 8*bl+7
#pragma unroll
        for (int q = 0; q < 8; ++q) tile[wid][8 * bl + q] = acc[q];
    }
    __syncthreads();

    // Coalesced epilogue: 8 consecutive lanes -> 8 consecutive j (32B segments).
#pragma unroll
    for (int i = tid; i < B_DIM * J_BLK; i += THREADS) {
        const int bb = i >> 3;
        const int jj = i & (J_BLK - 1);
        const float v = tile[jj][bb] + bias[j0 + jj];
        y[(size_t)bb * N_OUT + (j0 + jj)] = fmaxf(v, 0.f);
    }
}

// Fallback (no usable workspace): per-output wave, fp32 gathers from row-major x.
__global__ __launch_bounds__(THREADS) void sparse_layer_fallback(
        const float* __restrict__ x, const float* __restrict__ w,
        const float* __restrict__ bias, const int* __restrict__ src,
        const int* __restrict__ dst, float* __restrict__ y) {
    __shared__ float tile[J_BLK][130];
    __shared__ int   srp[J_BLK + 1];

    const int tid  = threadIdx.x;
    const int wid  = tid >> 6;
    const int lane = tid & 63;
    const int j0   = blockIdx.x * J_BLK;

    if (tid <= J_BLK) srp[tid] = lower_bound_dev(dst, N_EDGES, j0 + tid);
    __syncthreads();

    const int e0 = srp[wid], e1 = srp[wid + 1];
    const int b0 = lane * 2;
    float acc0 = 0.f, acc1 = 0.f;
    for (int e = e0; e < e1; ++e) {
        const int   s  = src[e];
        const float wt = w[e];
        acc0 = fmaf(x[(size_t)b0 * N_IN + s], wt, acc0);
        acc1 = fmaf(x[(size_t)(b0 + 1) * N_IN + s], wt, acc1);
    }
    tile[wid][b0]     = acc0;
    tile[wid][b0 + 1] = acc1;
    __syncthreads();
#pragma unroll
    for (int i = tid; i < B_DIM * J_BLK; i += THREADS) {
        const int bb = i >> 3;
        const int jj = i & (J_BLK - 1);
        const float v = tile[jj][bb] + bias[j0 + jj];
        y[(size_t)bb * N_OUT + (j0 + jj)] = fmaxf(v, 0.f);
    }
}

extern "C" void kernel_launch(void* const* d_in, const int* in_sizes, int n_in,
                              void* d_out, int out_size, void* d_ws, size_t ws_size,
                              hipStream_t stream) {
    const float* x    = (const float*)d_in[0];
    const float* w    = (const float*)d_in[1];
    const float* bias = (const float*)d_in[2];
    const int*   esrc = (const int*)d_in[3];
    const int*   edst = (const int*)d_in[4];
    float*       y    = (float*)d_out;

    const size_t RP_BYTES = (size_t)(N_OUT + 1) * sizeof(int);
    const size_t XT_OFF   = 65536;
    const size_t XT_BYTES = (size_t)N_IN * B_DIM * sizeof(__half);   // 4 MB

    const bool has_ws = ws_size >= XT_OFF + XT_BYTES && ws_size >= RP_BYTES;

    int*    rp  = (int*)d_ws;
    __half* xTh = (__half*)((char*)d_ws + XT_OFF);

    if (has_ws) {
        build_rowptr_kernel<<<(N_EDGES + 255) / 256, 256, 0, stream>>>(edst, rp);
        transpose_h_kernel<<<dim3(N_IN / 32, B_DIM / 64), dim3(32, 8), 0, stream>>>(x, xTh);
        sparse_layer_h<<<dim3(JGROUPS), THREADS, 0, stream>>>(xTh, w, bias, esrc, rp, y);
    } else {
        sparse_layer_fallback<<<dim3(N_OUT / J_BLK), THREADS, 0, stream>>>(x, w, bias, esrc, edst, y);
    }
}